// Round 16
// baseline (76.752 us; speedup 1.0000x reference)
//
#include <hip/hip_runtime.h>
#include <math.h>
#include <stdint.h>

#define HIDDEN  4096
#define NEXP    64
#define TOKS    64                 // tokens per block
#define KCH     128                // k floats per staged chunk
#define NCHK    (HIDDEN / KCH)     // 32 chunks
#define X_FL    (TOKS * KCH)       // 8192 floats: X region (32 KB)
#define PAR_FL  16384              // + Bhi 16KB + Blo 16KB = 64 KB per parity

typedef __bf16 bf16x8 __attribute__((ext_vector_type(8)));
typedef float  f32x4  __attribute__((ext_vector_type(4)));

union BfU { uint4 u; bf16x8 b; };

// fp32 -> (hi, lo) bf16 split; dropped lo*lo term ~2^-18 rel (R8-R15 verified).
static __device__ __forceinline__ void cvt_hilo(const float* x8, bf16x8& hi, bf16x8& lo) {
#pragma unroll
    for (int j = 0; j < 8; ++j) {
        const float x = x8[j];
        const __bf16 h = (__bf16)x;
        const float  r = x - (float)h;
        hi[j] = h;
        lo[j] = (__bf16)r;
    }
}

// async global->LDS, 16B/lane, wave-uniform dest base + lane*16
__device__ __forceinline__ void gload_lds16(const void* g, void* l) {
    __builtin_amdgcn_global_load_lds(
        (const __attribute__((address_space(1))) void*)g,
        (__attribute__((address_space(3))) void*)l, 16, 0, 0);
}

// ---- single-kernel bf16x3 MFMA router. R14's main loop VERBATIM (equal-best
// 70.6us; R10==R14 proved sync-structure-neutral) with the wconv pre-kernel
// DELETED: each wave gathers its B-fragment's 2KB of W fp32 straight from L2
// (W=1MB, hot on every XCD), cvt_hilo's it, and ds_writes the hi/lo frags in
// the exact LDS layout compute already reads. Pipelined 1 chunk ahead in
// static-named regs (rule #20): load W(c+2) in iter c; cvt+write B(c+1) into
// parity 1-p right after B1 (nobody reads 1-p during iter c; prior reads
// retired -- MFMA consumption forces lgkm before B1; lgkmcnt(0) before B2
// publishes my writes ahead of B1@c+1). Saves the second dispatch + gap.
__global__ __launch_bounds__(1024, 1) void router_mfma_kernel(
    const float* __restrict__ X,
    const float* __restrict__ W,
    const float* __restrict__ Bv, float* __restrict__ out, int nTok)
{
    __shared__ float smem[2 * PAR_FL];   // 131072 B; epilogue aliases

    const int tid = threadIdx.x;
    const int wv  = tid >> 6;
    const int tg  = wv >> 2;        // token-group 0..3
    const int kh  = wv & 3;         // k-step within chunk 0..3
    const int l   = tid & 63;
    const int g   = l >> 4;         // k-slot group 0..3
    const int cr  = l & 15;         // A row / B col within tile
    const int t0  = blockIdx.x * TOKS;

    // X staging (R10/R14-verified): 32 instrs, 2 per wave; instr q=2wv+r covers
    // rows 2q,2q+1 (512B each). Lane l: row = 2q+(l>>5), granule (l&31)^(row&7).
    const float* XgS[2];
    int xdst[2];
#pragma unroll
    for (int r = 0; r < 2; ++r) {
        const int q   = 2 * wv + r;
        const int row = 2 * q + (l >> 5);
        XgS[r]  = X + (size_t)(t0 + row) * HIDDEN + (((l & 31) ^ (row & 7)) << 2);
        xdst[r] = 2 * q * KCH;      // uniform base; HW adds lane*16B
    }

    // W gather (replaces wconv): wave wv owns frag f=wv of each chunk window
    // (e = wv&3, s_loc = wv>>2). Lane l reads W[16e + cr][32*(4c+s_loc) + 8g + j],
    // j=0..7 (2 dwordx4, L2-resident). Dest (floats): hi X_FL + wv*256 + l*4;
    // lo +4096. Identical fragment order to the R8-verified wconv output.
    const float* Wg  = W + (size_t)(16 * (wv & 3) + cr) * HIDDEN + 32 * (wv >> 2) + 8 * g;
    const int bHiDst = X_FL + wv * 256 + l * 4;          // float offsets
    const int bLoDst = bHiDst + 4096;

    // A-frag read (R10/R14-verified): row 16tg+cr; k-step kh; granule
    // 8kh + ((2g+h)^(cr&7)).
    const int m8   = cr & 7;
    const int rowX = (16 * tg + cr) * KCH;
    const int gA0  = (8 * kh + ((2 * g + 0) ^ m8)) << 2;
    const int gA1  = (8 * kh + ((2 * g + 1) ^ m8)) << 2;

    f32x4 acc[4] = {{0.f,0.f,0.f,0.f},{0.f,0.f,0.f,0.f},{0.f,0.f,0.f,0.f},{0.f,0.f,0.f,0.f}};
    float4 wSa0, wSa1, wSb0, wSb1;   // W fp32 pipeline regs (static names)

    // ---- prologue: W(0)->wSa; stage X(0),X(1); write B(0); W(1)->wSb
    wSa0 = *(const float4*)(Wg);
    wSa1 = *(const float4*)(Wg + 4);
#pragma unroll
    for (int r = 0; r < 2; ++r) gload_lds16(XgS[r], smem + xdst[r]);
#pragma unroll
    for (int r = 0; r < 2; ++r) gload_lds16(XgS[r] + KCH, smem + PAR_FL + xdst[r]);
    asm volatile("s_waitcnt vmcnt(4)" ::: "memory");   // W(0) regs landed
    {
        float x8[8];
        *(float4*)&x8[0] = wSa0; *(float4*)&x8[4] = wSa1;
        BfU hi, lo; cvt_hilo(x8, hi.b, lo.b);
        *(uint4*)&smem[bHiDst] = hi.u;
        *(uint4*)&smem[bLoDst] = lo.u;
    }
    wSb0 = *(const float4*)(Wg + KCH);
    wSb1 = *(const float4*)(Wg + KCH + 4);
    asm volatile("s_waitcnt lgkmcnt(0)" ::: "memory");  // B(0) writes drained

    // one iteration: consumes W regs (s0,s1) for B(c+1); loads W(c+2) into (d0,d1)
    auto iter = [&](int c, float4& s0, float4& s1, float4& d0, float4& d1) {
        asm volatile("s_waitcnt vmcnt(0)" ::: "memory");
        __builtin_amdgcn_s_barrier();          // B1: chunk c staged & visible
        const int p = c & 1;
        if (c + 1 < NCHK) {                    // cvt+write B(c+1) -> parity 1-p
            float* bb = smem + ((c + 1) & 1) * PAR_FL;
            float x8[8];
            *(float4*)&x8[0] = s0; *(float4*)&x8[4] = s1;
            BfU hi, lo; cvt_hilo(x8, hi.b, lo.b);
            *(uint4*)&bb[bHiDst] = hi.u;
            *(uint4*)&bb[bLoDst] = lo.u;
        }
        if (c + 2 < NCHK) {                    // load W(c+2) -> dest regs
            d0 = *(const float4*)(Wg + (size_t)(c + 2) * KCH);
            d1 = *(const float4*)(Wg + (size_t)(c + 2) * KCH + 4);
        }
        {   // compute c from parity p (R14 verbatim)
            const float*  xb = smem + p * PAR_FL;
            const ushort* bh = (const ushort*)(xb + X_FL) + (4 * kh) * 512 + l * 8;
            const ushort* bl = bh + 8192;      // Blo region (+16KB)
            float x8[8];
            *(float4*)&x8[0] = *(const float4*)(xb + rowX + gA0);
            *(float4*)&x8[4] = *(const float4*)(xb + rowX + gA1);
            bf16x8 xh, xo; cvt_hilo(x8, xh, xo);
#pragma unroll
            for (int e = 0; e < 4; ++e) {
                BfU ph, pl;
                ph.u = *(const uint4*)(bh + e * 512);
                pl.u = *(const uint4*)(bl + e * 512);
                acc[e] = __builtin_amdgcn_mfma_f32_16x16x32_bf16(xh, ph.b, acc[e], 0, 0, 0);
                acc[e] = __builtin_amdgcn_mfma_f32_16x16x32_bf16(xo, ph.b, acc[e], 0, 0, 0);
                acc[e] = __builtin_amdgcn_mfma_f32_16x16x32_bf16(xh, pl.b, acc[e], 0, 0, 0);
            }
        }
        asm volatile("s_waitcnt lgkmcnt(0)" ::: "memory");  // B(c+1) writes drained
        __builtin_amdgcn_s_barrier();          // B2: all reads of parity p done
        if (c + 2 < NCHK) {                    // stage X(c+2) -> parity p (freed)
            float* pb = smem + p * PAR_FL;
            const int ko = (c + 2) * KCH;
#pragma unroll
            for (int r = 0; r < 2; ++r) gload_lds16(XgS[r] + ko, pb + xdst[r]);
        }
    };

#pragma unroll 1
    for (int cc = 0; cc < NCHK; cc += 2) {
        iter(cc,     wSb0, wSb1, wSa0, wSa1);   // even c: consume wSb, load wSa
        iter(cc + 1, wSa0, wSa1, wSb0, wSb1);   // odd  c: consume wSa, load wSb
    }

    __syncthreads();   // full drain; safe to alias LDS for epilogue

    // ---- epilogue (R8-R15 verified), LDS aliased: tiles 69632B + tt 16640B
    float (*tiles)[64][68] = (float (*)[64][68])smem;
    float* tt = smem + 4 * 64 * 68;

    // C/D layout (m89): row = 16tg + 4g + i, col = 16e + cr
#pragma unroll
    for (int e = 0; e < 4; ++e)
#pragma unroll
        for (int i = 0; i < 4; ++i)
            tiles[kh][16 * tg + 4 * g + i][16 * e + cr] = acc[e][i];
    __syncthreads();

    const size_t offSel = (size_t)nTok * 2;
    const size_t offLog = (size_t)nTok * 4;

    // combine 4 K-split partials + bias; store logits; build transposed tile
    {
        const int tok = tid >> 4;          // 0..63
        const int e4  = (tid & 15) * 4;
        const float4 s0 = *(const float4*)&tiles[0][tok][e4];
        const float4 s1 = *(const float4*)&tiles[1][tok][e4];
        const float4 s2 = *(const float4*)&tiles[2][tok][e4];
        const float4 s3 = *(const float4*)&tiles[3][tok][e4];
        const float4 bb = *(const float4*)(Bv + e4);
        const float4 r = make_float4(s0.x + s1.x + s2.x + s3.x + bb.x,
                                     s0.y + s1.y + s2.y + s3.y + bb.y,
                                     s0.z + s1.z + s2.z + s3.z + bb.z,
                                     s0.w + s1.w + s2.w + s3.w + bb.w);
        *(float4*)(out + offLog + (size_t)(t0 + tok) * NEXP + e4) = r;
        tt[(e4 + 0) * 65 + tok] = r.x;
        tt[(e4 + 1) * 65 + tok] = r.y;
        tt[(e4 + 2) * 65 + tok] = r.z;
        tt[(e4 + 3) * 65 + tok] = r.w;
    }
    __syncthreads();

    // top-2 + softmax (verified): strict > keeps lowest index on ties
    if (tid < 64) {
        const int t = tid;
        float m1 = -INFINITY, m2 = -INFINITY;
        int i1 = 0, i2 = 0;
#pragma unroll
        for (int e = 0; e < NEXP; ++e) {
            const float v = tt[e * 65 + t];
            if (v > m1)      { m2 = m1; i2 = i1; m1 = v; i1 = e; }
            else if (v > m2) { m2 = v; i2 = e; }
        }
        const float ex  = expf(m2 - m1);
        const float inv = 1.0f / (1.0f + ex);
        *(float2*)(out + (size_t)(t0 + t) * 2)          = make_float2(inv, ex * inv);
        *(float2*)(out + offSel + (size_t)(t0 + t) * 2) = make_float2((float)i1, (float)i2);
    }

    if (blockIdx.x == 0 && tid == 0)
        out[offLog + (size_t)nTok * NEXP] = 0.0f;   // aux_loss
}

extern "C" void kernel_launch(void* const* d_in, const int* in_sizes, int n_in,
                              void* d_out, int out_size, void* d_ws, size_t ws_size,
                              hipStream_t stream)
{
    const float* X  = (const float*)d_in[0];
    const float* W  = (const float*)d_in[1];
    const float* Bv = (const float*)d_in[2];
    float* out = (float*)d_out;
    const int nTok = in_sizes[0] / HIDDEN;    // 16384
    router_mfma_kernel<<<nTok / TOKS, 1024, 0, stream>>>(X, W, Bv, out, nTok);
}

// Round 17
// 67.043 us; speedup vs baseline: 1.1448x; 1.1448x over previous
//
#include <hip/hip_runtime.h>
#include <math.h>
#include <stdint.h>

#define HIDDEN 4096
#define NEXP   64
#define TOKS   64                 // tokens per gemm block
#define KBLK   2048               // K per block (split-K x2)
#define KCH    64                 // k floats per staged chunk
#define NCHK   (KBLK / KCH)       // 32 chunks
#define X_FL   (TOKS * KCH)       // 4096 floats: X region (16 KB)
#define PAR_FL (X_FL + 2 * 2048)  // + Bhi 8KB + Blo 8KB = 8192 floats (32 KB)

typedef __bf16 bf16x8 __attribute__((ext_vector_type(8)));
typedef float  f32x4  __attribute__((ext_vector_type(4)));

union BfU { uint4 u; bf16x8 b; };

// fp32 -> (hi, lo) bf16 split; dropped lo*lo term ~2^-18 rel (R8-R16 verified).
static __device__ __forceinline__ void cvt_hilo(const float* x8, bf16x8& hi, bf16x8& lo) {
#pragma unroll
    for (int j = 0; j < 8; ++j) {
        const float x = x8[j];
        const __bf16 h = (__bf16)x;
        const float  r = x - (float)h;
        hi[j] = h;
        lo[j] = (__bf16)r;
    }
}

// async global->LDS, 16B/lane, wave-uniform dest base + lane*16
__device__ __forceinline__ void gload_lds16(const void* g, void* l) {
    __builtin_amdgcn_global_load_lds(
        (const __attribute__((address_space(1))) void*)g,
        (__attribute__((address_space(3))) void*)l, 16, 0, 0);
}

// ---- pre-kernel (R8-R16 verified): W fp32 -> B-fragment-ordered bf16 hi/lo.
// Fragment F = S*4 + e (S = k-step of 32): lane l supplies
// B[col 16e+(l&15)][k 32S+8(l>>4)+j] at ws[F*512 + l*8].
__global__ __launch_bounds__(512) void wconv_kernel(
    const float* __restrict__ W, ushort* __restrict__ wsHi, ushort* __restrict__ wsLo)
{
    const int gid = blockIdx.x * blockDim.x + threadIdx.x;   // 0..32767
    const int S = gid >> 8;
    const int e = (gid >> 6) & 3;
    const int l = gid & 63;
    const int row = 16 * e + (l & 15);
    const int k0  = 32 * S + 8 * (l >> 4);
    const float* src = W + (size_t)row * HIDDEN + k0;
    float x8[8];
    *(float4*)&x8[0] = *(const float4*)src;
    *(float4*)&x8[4] = *(const float4*)(src + 4);
    BfU hi, lo;
    cvt_hilo(x8, hi.b, lo.b);
    const size_t o = ((size_t)(S * 4 + e) * 64 + l) * 8;
    *(uint4*)(wsHi + o) = hi.u;
    *(uint4*)(wsLo + o) = lo.u;
}

// ---- gemm half: R14's counted-vmcnt 2-barrier pipeline at HALF scale so
// TWO blocks co-reside per CU (512 blocks = 256 tiles x 2 K-halves; LDS
// 64KB/block). Unconfounded probe of the convoy theory: R14's 16-wave
// single block stalls as a unit at B1 (max-of-16 straggler; CU HBM queue
// empties); here the co-resident block covers those windows. Each block
// stages only ITS K-half's B => per-CU B traffic == R14 (R12's confound
// removed). 8 waves = tg(4) x kh(2); acc[4]; vmcnt(4) + raw s_barrier
// (loads stay in flight across barriers). Raw 64x64 partial out (no bias).
__global__ __launch_bounds__(512, 2) void gemm_half_kernel(
    const float* __restrict__ X,
    const ushort* __restrict__ wsHi, const ushort* __restrict__ wsLo,
    float* __restrict__ outLog, float* __restrict__ wsP, int nTok)
{
    __shared__ float smem[2 * PAR_FL];   // 65536 B; epilogue aliases

    const int tid = threadIdx.x;
    const int wv  = tid >> 6;        // 0..7
    const int tg  = wv >> 1;         // token-group 0..3
    const int kh  = wv & 1;          // k-step within chunk 0..1
    const int l   = tid & 63;
    const int g   = l >> 4;          // k-slot group 0..3
    const int cr  = l & 15;          // A row / B col within tile
    const int bx  = blockIdx.x;
    const int h   = bx & 1;          // K-half
    const int t0  = (bx >> 1) * TOKS;

    // X staging (R13-verified KCH=64 forms): instr q=2wv+r covers rows
    // 4q..4q+3 (256B each); lane l -> row 4q+(l>>4), granule l&15; source
    // granule (l&8)|((l&7)^(row&7)) (involution).
    const float* XgS[2];
    int xdst[2];
#pragma unroll
    for (int r = 0; r < 2; ++r) {
        const int q    = 2 * wv + r;
        const int srow = 4 * q + (l >> 4);
        const int sgr  = (l & 8) | ((l & 7) ^ (srow & 7));
        XgS[r]  = X + (size_t)(t0 + srow) * HIDDEN + h * KBLK + sgr * 4;
        xdst[r] = 4 * q * KCH;       // floats (uniform base)
    }
    // B staging: chunk window = frags [h*256 + 8c, +8) per plane; wave wv
    // stages hi frag slot wv and lo frag slot wv (1KB linear each).
    const ushort* BhS = wsHi + (size_t)h * 131072 + (size_t)wv * 512 + (size_t)l * 8;
    const ushort* BlS = wsLo + (size_t)h * 131072 + (size_t)wv * 512 + (size_t)l * 8;
    const int bhdst = X_FL + wv * 256;
    const int bldst = X_FL + 2048 + wv * 256;

    // A-frag read: row 16tg+cr; k-step kh; granule 8kh + ((2g+h')^(cr&7)).
    const int m8   = cr & 7;
    const int rowX = (16 * tg + cr) * KCH;
    const int gA0  = (8 * kh + ((2 * g + 0) ^ m8)) << 2;
    const int gA1  = (8 * kh + ((2 * g + 1) ^ m8)) << 2;

    f32x4 acc[4] = {{0.f,0.f,0.f,0.f},{0.f,0.f,0.f,0.f},{0.f,0.f,0.f,0.f},{0.f,0.f,0.f,0.f}};

    // prologue: stage chunk 0 -> parity 0, chunk 1 -> parity 1
#pragma unroll
    for (int r = 0; r < 2; ++r) gload_lds16(XgS[r], smem + xdst[r]);
    gload_lds16(BhS, smem + bhdst);
    gload_lds16(BlS, smem + bldst);
#pragma unroll
    for (int r = 0; r < 2; ++r) gload_lds16(XgS[r] + KCH, smem + PAR_FL + xdst[r]);
    gload_lds16(BhS + 4096, smem + PAR_FL + bhdst);
    gload_lds16(BlS + 4096, smem + PAR_FL + bldst);

#pragma unroll 1
    for (int c = 0; c < NCHK; ++c) {
        if (c + 1 < NCHK) asm volatile("s_waitcnt vmcnt(4)" ::: "memory");
        else              asm volatile("s_waitcnt vmcnt(0)" ::: "memory");
        __builtin_amdgcn_s_barrier();          // B1: chunk c staged & visible
        const int p = c & 1;
        {
            const float*  xb = smem + p * PAR_FL;
            const ushort* bh = (const ushort*)(xb + X_FL) + (4 * kh) * 512 + l * 8;
            const ushort* bl = bh + 4096;      // Blo region (+2048 floats)
            float x8[8];
            *(float4*)&x8[0] = *(const float4*)(xb + rowX + gA0);
            *(float4*)&x8[4] = *(const float4*)(xb + rowX + gA1);
            bf16x8 xh, xo; cvt_hilo(x8, xh, xo);
#pragma unroll
            for (int e = 0; e < 4; ++e) {
                BfU ph, pl;
                ph.u = *(const uint4*)(bh + e * 512);
                pl.u = *(const uint4*)(bl + e * 512);
                acc[e] = __builtin_amdgcn_mfma_f32_16x16x32_bf16(xh, ph.b, acc[e], 0, 0, 0);
                acc[e] = __builtin_amdgcn_mfma_f32_16x16x32_bf16(xo, ph.b, acc[e], 0, 0, 0);
                acc[e] = __builtin_amdgcn_mfma_f32_16x16x32_bf16(xh, pl.b, acc[e], 0, 0, 0);
            }
        }
        __builtin_amdgcn_s_barrier();          // B2: all reads of parity p done
        if (c + 2 < NCHK) {                    // issue c+2 -> parity p (freed)
            float* pb = smem + p * PAR_FL;
            const int ko = (c + 2) * KCH;
            const size_t bo = (size_t)(c + 2) * 4096;
#pragma unroll
            for (int r = 0; r < 2; ++r) gload_lds16(XgS[r] + ko, pb + xdst[r]);
            gload_lds16(BhS + bo, pb + bhdst);
            gload_lds16(BlS + bo, pb + bldst);
        }
    }

    __syncthreads();   // full drain; safe to alias LDS

    // ---- combine kh partials in LDS; write raw 64x64 partial (no bias)
    float (*tiles)[64][68] = (float (*)[64][68])smem;   // 2*64*68 floats
#pragma unroll
    for (int e = 0; e < 4; ++e)
#pragma unroll
        for (int i = 0; i < 4; ++i)
            tiles[kh][16 * tg + 4 * g + i][16 * e + cr] = acc[e][i];   // C/D (m89)
    __syncthreads();

    {
        float* dst = (h ? wsP : outLog) + (size_t)t0 * NEXP;
        const int tok = tid >> 3;          // 0..63
        const int e8  = (tid & 7) * 8;
        float v[8];
#pragma unroll
        for (int j = 0; j < 8; ++j)
            v[j] = tiles[0][tok][e8 + j] + tiles[1][tok][e8 + j];
        float* rowp = dst + (size_t)tok * NEXP + e8;
        *(float4*)rowp       = make_float4(v[0], v[1], v[2], v[3]);
        *(float4*)(rowp + 4) = make_float4(v[4], v[5], v[6], v[7]);
    }
}

// Combine (R7-verified): logits = partial0 (logits region) + partial1 (ws)
// + bias; top-2 + softmax, strict > keeps lowest index (jax top_k).
__global__ __launch_bounds__(256) void combine_kernel(
    const float* __restrict__ wsP,
    const float* __restrict__ Bv,
    float* __restrict__ out, int nTok)
{
    __shared__ float tt[64 * 65];
    const int tid = threadIdx.x;
    const int t0  = blockIdx.x * TOKS;
    const size_t offSel = (size_t)nTok * 2;
    const size_t offLog = (size_t)nTok * 4;
    float*       L = out + offLog + (size_t)t0 * NEXP;
    const float* P = wsP + (size_t)t0 * NEXP;

#pragma unroll
    for (int r = 0; r < 4; ++r) {
        const int idx = r * 256 + tid;        // 0..1023 float4-chunks
        const int tok = idx >> 4;
        const int e4  = (idx & 15) * 4;
        const float4 a  = *(const float4*)(L + tok * NEXP + e4);
        const float4 b  = *(const float4*)(P + tok * NEXP + e4);
        const float4 bb = *(const float4*)(Bv + e4);
        const float4 s = make_float4(a.x + b.x + bb.x, a.y + b.y + bb.y,
                                     a.z + b.z + bb.z, a.w + b.w + bb.w);
        *(float4*)(L + tok * NEXP + e4) = s;
        tt[(e4 + 0) * 65 + tok] = s.x;
        tt[(e4 + 1) * 65 + tok] = s.y;
        tt[(e4 + 2) * 65 + tok] = s.z;
        tt[(e4 + 3) * 65 + tok] = s.w;
    }
    __syncthreads();

    if (tid < 64) {
        const int t = tid;
        float m1 = -INFINITY, m2 = -INFINITY;
        int i1 = 0, i2 = 0;
#pragma unroll
        for (int e = 0; e < NEXP; ++e) {
            const float v = tt[e * 65 + t];
            if (v > m1)      { m2 = m1; i2 = i1; m1 = v; i1 = e; }
            else if (v > m2) { m2 = v; i2 = e; }
        }
        const float ex  = expf(m2 - m1);
        const float inv = 1.0f / (1.0f + ex);
        *(float2*)(out + (size_t)(t0 + tid) * 2)          = make_float2(inv, ex * inv);
        *(float2*)(out + offSel + (size_t)(t0 + tid) * 2) = make_float2((float)i1, (float)i2);
    }

    if (blockIdx.x == 0 && tid == 0)
        out[offLog + (size_t)nTok * NEXP] = 0.0f;   // aux_loss
}

extern "C" void kernel_launch(void* const* d_in, const int* in_sizes, int n_in,
                              void* d_out, int out_size, void* d_ws, size_t ws_size,
                              hipStream_t stream)
{
    const float* X  = (const float*)d_in[0];
    const float* W  = (const float*)d_in[1];
    const float* Bv = (const float*)d_in[2];
    float* out = (float*)d_out;
    const int nTok  = in_sizes[0] / HIDDEN;   // 16384
    const int tiles = nTok / TOKS;            // 256
    ushort* wsHi = (ushort*)d_ws;             // 512 KB
    ushort* wsLo = wsHi + (size_t)NEXP * HIDDEN;     // 512 KB
    float*  wsP  = (float*)(wsLo + (size_t)NEXP * HIDDEN);  // 4 MB partials
    float*  outLog = out + (size_t)nTok * 4;

    wconv_kernel<<<256, 128, 0, stream>>>(W, wsHi, wsLo);
    gemm_half_kernel<<<2 * tiles, 512, 0, stream>>>(X, wsHi, wsLo, outLog, wsP, nTok);
    combine_kernel<<<tiles, 256, 0, stream>>>(wsP, Bv, out, nTok);
}